// Round 3
// baseline (138.891 us; speedup 1.0000x reference)
//
#include <hip/hip_runtime.h>
#include <hip/hip_bf16.h>
#include <math.h>

// Model_58488864637193 — algebraic collapse of the 3 stacked linears:
//   Wc = W1 @ (Ws @ Wr)  [32,4],  bc = (b1 @ (Ws@Wr)) + bs@Wr + br  [4]
// Work: 141 GFLOP -> ~1.1 GFLOP, dominated by the ring-121 484->32 tanh layer.
//
// R2 -> R3: stage1 was LDS-throughput-bound (9 ds_read_b128 per 32 FMA,
// ~43 us). Weights are wave-uniform (wave = one 8-neuron oct x 64 rows), so
// route them through the SCALAR pipe: readfirstlane-forced uniform loads ->
// s_load into SGPRs, v_fmac with SGPR operand. W0 LDS staging deleted; LDS
// keeps only the x halo (1 ds_read_b128 per thread per d, ~5 us).

#define L_SEQ 4096
#define TL    64    // output rows per stage1 block

// ---------------- precomp1: T[513][4] = [Ws; bs] @ Wr ----------------
__global__ __launch_bounds__(256) void precomp1_kernel(
    const float* __restrict__ Ws, const float* __restrict__ bs,
    const float* __restrict__ Wr, float* __restrict__ T) {
  const int tid  = threadIdx.x;
  const int k    = blockIdx.x * 4 + (tid >> 6);   // wave id = output row
  const int lane = tid & 63;
  if (k >= 513) return;
  const float4* row4 = (const float4*)((k < 512) ? (Ws + (size_t)k * 4096) : bs);
  const float4* Wr4  = (const float4*)Wr;
  float a0 = 0.f, a1 = 0.f, a2 = 0.f, a3 = 0.f;
  for (int m4 = lane; m4 < 1024; m4 += 64) {
    const float4 rv = row4[m4];
#pragma unroll
    for (int c = 0; c < 4; ++c) {
      const float  xs = ((const float*)&rv)[c];
      const float4 w  = Wr4[m4 * 4 + c];
      a0 = fmaf(xs, w.x, a0); a1 = fmaf(xs, w.y, a1);
      a2 = fmaf(xs, w.z, a2); a3 = fmaf(xs, w.w, a3);
    }
  }
#pragma unroll
  for (int off = 32; off > 0; off >>= 1) {
    a0 += __shfl_xor(a0, off); a1 += __shfl_xor(a1, off);
    a2 += __shfl_xor(a2, off); a3 += __shfl_xor(a3, off);
  }
  if (lane == 0) {
    float4 o; o.x = a0; o.y = a1; o.z = a2; o.w = a3;
    ((float4*)T)[k] = o;
  }
}

// ---------------- precomp2: WcBc[132] = {Wc[32][4] row-major, bc[4]} ----------------
__global__ __launch_bounds__(128) void precomp2_kernel(
    const float* __restrict__ W1, const float* __restrict__ b1,
    const float* __restrict__ br, const float* __restrict__ T,
    float* __restrict__ WcBc) {
  const int i   = blockIdx.x;        // 0..32
  const int t   = threadIdx.x;       // 0..127
  const int j   = t & 3;
  const int seg = t >> 2;            // 0..31
  const float4* v4 = (const float4*)((i < 32) ? (W1 + (size_t)i * 512) : b1);
  const float4* T4 = (const float4*)T;
  float acc = 0.f;
#pragma unroll
  for (int q = 0; q < 4; ++q) {
    const int m4 = seg * 4 + q;
    const float4 vv = v4[m4];
#pragma unroll
    for (int c = 0; c < 4; ++c) {
      const float4 trow = T4[m4 * 4 + c];
      acc = fmaf(((const float*)&vv)[c], ((const float*)&trow)[j], acc);
    }
  }
  __shared__ float red[128];
  red[t] = acc;
  __syncthreads();
#pragma unroll
  for (int s = 64; s >= 4; s >>= 1) {
    if (t < s) red[t] += red[t + s];
    __syncthreads();
  }
  if (t < 4) {
    float r = red[t];
    if (i == 32) r += T[512 * 4 + t] + br[t];
    WcBc[(i < 32 ? i * 4 : 128) + t] = r;
  }
}

// ---------------- stage1: y = tanh(win121(x) @ W0 + b0) @ Wc + bc ----------------
// 512 blocks (8 batches x 64 tiles), 256 threads = 4 waves; wave = one
// 8-neuron oct x 64 rows. Weights via uniform (scalar-pipe) loads.
__global__ __launch_bounds__(256) void stage1_kernel(
    const float* __restrict__ x, const float* __restrict__ W0,
    const float* __restrict__ b0, const float* __restrict__ WcBc,
    float* __restrict__ y) {
  __shared__ float4 sXv[TL + 120];      // 184 * 16 B = 2944 B
  __shared__ float4 sY[256];            // per-thread partial y, 4096 B
  __shared__ float  sWc[132];           // Wc + bc

  const int b    = blockIdx.x >> 6;     // 8 batches x 64 tiles
  const int tile = blockIdx.x & 63;
  const int l0   = tile * TL;
  const int tid  = threadIdx.x;

  const float4* xv = (const float4*)(x + (size_t)b * L_SEQ * 4);
  for (int i = tid; i < TL + 120; i += 256)
    sXv[i] = xv[(l0 - 120 + i) & (L_SEQ - 1)];
  if (tid < 132) sWc[tid] = WcBc[tid];
  __syncthreads();

  const int lane = tid & 63;                              // row within tile
  const int octu = __builtin_amdgcn_readfirstlane(tid >> 6); // 0..3, uniform
  const float* __restrict__ Wb = W0 + octu * 8;           // neuron-group base

  float acc[8];
#pragma unroll
  for (int n = 0; n < 8; ++n) acc[n] = b0[octu * 8 + n];  // uniform loads

  for (int d = 0; d < 121; ++d) {
    const float4 xc = sXv[lane + d];                      // 1 ds_read_b128
#pragma unroll
    for (int c = 0; c < 4; ++c) {
      const float* wr = Wb + (size_t)(d * 4 + c) * 32;    // uniform address
      const float4 w0 = *(const float4*)(wr);             // -> s_load_dwordx4
      const float4 w1 = *(const float4*)(wr + 4);
      const float xs = ((const float*)&xc)[c];
      acc[0] = fmaf(xs, w0.x, acc[0]); acc[1] = fmaf(xs, w0.y, acc[1]);
      acc[2] = fmaf(xs, w0.z, acc[2]); acc[3] = fmaf(xs, w0.w, acc[3]);
      acc[4] = fmaf(xs, w1.x, acc[4]); acc[5] = fmaf(xs, w1.y, acc[5]);
      acc[6] = fmaf(xs, w1.z, acc[6]); acc[7] = fmaf(xs, w1.w, acc[7]);
    }
  }

  // fast tanh + fold through Wc (partial over this wave's 8 neurons)
  float4 yp; yp.x = 0.f; yp.y = 0.f; yp.z = 0.f; yp.w = 0.f;
#pragma unroll
  for (int n = 0; n < 8; ++n) {
    const float h = 1.f - 2.f / (__expf(2.f * acc[n]) + 1.f);
    const int nb = (octu * 8 + n) * 4;
    yp.x = fmaf(h, sWc[nb + 0], yp.x); yp.y = fmaf(h, sWc[nb + 1], yp.y);
    yp.z = fmaf(h, sWc[nb + 2], yp.z); yp.w = fmaf(h, sWc[nb + 3], yp.w);
  }
  sY[tid] = yp;
  __syncthreads();

  if (tid < TL) {
    const float4 p0 = sY[tid], p1 = sY[tid + 64], p2 = sY[tid + 128],
                 p3 = sY[tid + 192];
    float4 out;
    out.x = p0.x + p1.x + p2.x + p3.x + sWc[128 + 0];
    out.y = p0.y + p1.y + p2.y + p3.y + sWc[128 + 1];
    out.z = p0.z + p1.z + p2.z + p3.z + sWc[128 + 2];
    out.w = p0.w + p1.w + p2.w + p3.w + sWc[128 + 3];
    ((float4*)(y + (size_t)b * L_SEQ * 4))[l0 + tid] = out;
  }
}

// ---------------- stage2: out = relu(win5(y) @ W2 + b2) @ W3 + b3 ----------------
__global__ __launch_bounds__(256) void stage2_kernel(
    const float* __restrict__ y, const float* __restrict__ W2,
    const float* __restrict__ b2, const float* __restrict__ W3,
    const float* __restrict__ b3, float* __restrict__ out) {
  const int g = blockIdx.x * 256 + threadIdx.x;  // 0..32767
  const int b = g >> 12;
  const int l = g & (L_SEQ - 1);
  const float4* yv = (const float4*)(y + (size_t)b * L_SEQ * 4);

  float win[20];
#pragma unroll
  for (int j = 0; j < 5; ++j) {
    const float4 v = yv[(l - 4 + j) & (L_SEQ - 1)];
    win[j*4+0] = v.x; win[j*4+1] = v.y; win[j*4+2] = v.z; win[j*4+3] = v.w;
  }

  float h[32];
#pragma unroll
  for (int n = 0; n < 32; ++n) h[n] = b2[n];
#pragma unroll
  for (int k = 0; k < 20; ++k) {
    const float xs = win[k];
#pragma unroll
    for (int n = 0; n < 32; ++n) h[n] = fmaf(xs, W2[k*32 + n], h[n]);
  }

  float o[4];
#pragma unroll
  for (int j = 0; j < 4; ++j) o[j] = b3[j];
#pragma unroll
  for (int n = 0; n < 32; ++n) {
    const float hv = fmaxf(h[n], 0.f);
#pragma unroll
    for (int j = 0; j < 4; ++j) o[j] = fmaf(hv, W3[n*4 + j], o[j]);
  }
  float4 ov;
  ((float*)&ov)[0] = o[0]; ((float*)&ov)[1] = o[1];
  ((float*)&ov)[2] = o[2]; ((float*)&ov)[3] = o[3];
  ((float4*)out)[g] = ov;
}

extern "C" void kernel_launch(void* const* d_in, const int* in_sizes, int n_in,
                              void* d_out, int out_size, void* d_ws, size_t ws_size,
                              hipStream_t stream) {
  const float* x  = (const float*)d_in[0];   // [8,4096,4]
  const float* W0 = (const float*)d_in[1];   // [484,32]
  const float* b0 = (const float*)d_in[2];   // [32]
  const float* W1 = (const float*)d_in[3];   // [32,512]
  const float* b1 = (const float*)d_in[4];   // [512]
  const float* Ws = (const float*)d_in[5];   // [512,4096]
  const float* bs = (const float*)d_in[6];   // [4096]
  const float* Wr = (const float*)d_in[7];   // [4096,4]
  const float* br = (const float*)d_in[8];   // [4]
  const float* W2 = (const float*)d_in[9];   // [20,32]
  const float* b2 = (const float*)d_in[10];  // [32]
  const float* W3 = (const float*)d_in[11];  // [32,4]
  const float* b3 = (const float*)d_in[12];  // [4]
  float* outp = (float*)d_out;               // [8,4096,4]

  // workspace (floats): T[513*4]=2052 @0, WcBc[132] @2052, y[131072] @2304
  float* T    = (float*)d_ws;
  float* WcBc = T + 2052;
  float* y    = (float*)d_ws + 2304;   // 16B-aligned

  precomp1_kernel<<<129, 256, 0, stream>>>(Ws, bs, Wr, T);
  precomp2_kernel<<<33, 128, 0, stream>>>(W1, b1, br, T, WcBc);
  stage1_kernel<<<512, 256, 0, stream>>>(x, W0, b0, WcBc, y);
  stage2_kernel<<<128, 256, 0, stream>>>(y, W2, b2, W3, b3, outp);
}

// Round 4
// 136.767 us; speedup vs baseline: 1.0155x; 1.0155x over previous
//
#include <hip/hip_runtime.h>
#include <hip/hip_bf16.h>
#include <math.h>

// Model_58488864637193 — algebraic collapse of the 3 stacked linears:
//   Wc = W1 @ (Ws @ Wr)  [32,4],  bc = (b1 @ (Ws@Wr)) + bs@Wr + br  [4]
// Work: 141 GFLOP -> ~1.1 GFLOP, dominated by the ring-121 484->32 tanh layer.
//
// R3 -> R4: stage1 was scalar-load latency-bound (VALUBusy 16%): 8 s_loads ->
// wait -> 32 fmac per d. Now the 8 weight float4s are double-buffered in SGPRs
// (prefetch d+1 during d's FMAs, last iter peeled), hiding K$ latency under
// the 64-cyc FMA block. precomp1 gets unroll-4 ILP; stage2 regridded to 256
// blocks so every CU participates.

#define L_SEQ 4096
#define TL    64    // output rows per stage1 block (= wave width)

// ---------------- precomp1: T[513][4] = [Ws; bs] @ Wr ----------------
__global__ __launch_bounds__(256) void precomp1_kernel(
    const float* __restrict__ Ws, const float* __restrict__ bs,
    const float* __restrict__ Wr, float* __restrict__ T) {
  const int tid  = threadIdx.x;
  const int k    = blockIdx.x * 4 + (tid >> 6);   // wave id = output row
  const int lane = tid & 63;
  if (k >= 513) return;
  const float4* row4 = (const float4*)((k < 512) ? (Ws + (size_t)k * 4096) : bs);
  const float4* Wr4  = (const float4*)Wr;
  float a0 = 0.f, a1 = 0.f, a2 = 0.f, a3 = 0.f;
#pragma unroll 4
  for (int m4 = lane; m4 < 1024; m4 += 64) {
    const float4 rv = row4[m4];
#pragma unroll
    for (int c = 0; c < 4; ++c) {
      const float  xs = ((const float*)&rv)[c];
      const float4 w  = Wr4[m4 * 4 + c];
      a0 = fmaf(xs, w.x, a0); a1 = fmaf(xs, w.y, a1);
      a2 = fmaf(xs, w.z, a2); a3 = fmaf(xs, w.w, a3);
    }
  }
#pragma unroll
  for (int off = 32; off > 0; off >>= 1) {
    a0 += __shfl_xor(a0, off); a1 += __shfl_xor(a1, off);
    a2 += __shfl_xor(a2, off); a3 += __shfl_xor(a3, off);
  }
  if (lane == 0) {
    float4 o; o.x = a0; o.y = a1; o.z = a2; o.w = a3;
    ((float4*)T)[k] = o;
  }
}

// ---------------- precomp2: WcBc[132] = {Wc[32][4] row-major, bc[4]} ----------------
__global__ __launch_bounds__(128) void precomp2_kernel(
    const float* __restrict__ W1, const float* __restrict__ b1,
    const float* __restrict__ br, const float* __restrict__ T,
    float* __restrict__ WcBc) {
  const int i   = blockIdx.x;        // 0..32
  const int t   = threadIdx.x;       // 0..127
  const int j   = t & 3;
  const int seg = t >> 2;            // 0..31
  const float4* v4 = (const float4*)((i < 32) ? (W1 + (size_t)i * 512) : b1);
  const float4* T4 = (const float4*)T;
  float acc = 0.f;
#pragma unroll
  for (int q = 0; q < 4; ++q) {
    const int m4 = seg * 4 + q;
    const float4 vv = v4[m4];
#pragma unroll
    for (int c = 0; c < 4; ++c) {
      const float4 trow = T4[m4 * 4 + c];
      acc = fmaf(((const float*)&vv)[c], ((const float*)&trow)[j], acc);
    }
  }
  __shared__ float red[128];
  red[t] = acc;
  __syncthreads();
#pragma unroll
  for (int s = 64; s >= 4; s >>= 1) {
    if (t < s) red[t] += red[t + s];
    __syncthreads();
  }
  if (t < 4) {
    float r = red[t];
    if (i == 32) r += T[512 * 4 + t] + br[t];
    WcBc[(i < 32 ? i * 4 : 128) + t] = r;
  }
}

// ---------------- stage1: y = tanh(win121(x) @ W0 + b0) @ Wc + bc ----------------
// 512 blocks (8 batches x 64 tiles), 4 waves; wave = one 8-neuron oct x 64 rows.
// Weights stream through the scalar pipe, double-buffered in SGPRs.
__global__ __launch_bounds__(256) void stage1_kernel(
    const float* __restrict__ x, const float* __restrict__ W0,
    const float* __restrict__ b0, const float* __restrict__ WcBc,
    float* __restrict__ y) {
  __shared__ float4 sXv[TL + 120];      // 184 * 16 B
  __shared__ float4 sY[256];            // per-thread partial y
  __shared__ float  sWc[132];           // Wc + bc

  const int b    = blockIdx.x >> 6;     // 8 batches x 64 tiles
  const int tile = blockIdx.x & 63;
  const int l0   = tile * TL;
  const int tid  = threadIdx.x;

  const float4* xv = (const float4*)(x + (size_t)b * L_SEQ * 4);
  for (int i = tid; i < TL + 120; i += 256)
    sXv[i] = xv[(l0 - 120 + i) & (L_SEQ - 1)];
  if (tid < 132) sWc[tid] = WcBc[tid];
  __syncthreads();

  const int lane = tid & 63;                                 // row within tile
  const int octu = __builtin_amdgcn_readfirstlane(tid >> 6); // 0..3, uniform
  const float* __restrict__ Wb = W0 + octu * 8;              // neuron-group base

  float acc[8];
#pragma unroll
  for (int n = 0; n < 8; ++n) acc[n] = b0[octu * 8 + n];     // uniform loads

  // SGPR double-buffer: wn holds weights for the NEXT d while wc feeds FMAs.
  float4 wn[8];
#pragma unroll
  for (int q = 0; q < 8; ++q)
    wn[q] = *(const float4*)(Wb + (q >> 1) * 32 + (q & 1) * 4);

  for (int d = 0; d < 120; ++d) {
    float4 wc[8];
#pragma unroll
    for (int q = 0; q < 8; ++q) wc[q] = wn[q];
    const float* Wd = Wb + (size_t)(d + 1) * 128;            // rows 4(d+1)..+3
#pragma unroll
    for (int q = 0; q < 8; ++q)
      wn[q] = *(const float4*)(Wd + (q >> 1) * 32 + (q & 1) * 4);
    const float4 xc = sXv[lane + d];                         // 1 ds_read_b128
#pragma unroll
    for (int c = 0; c < 4; ++c) {
      const float xs = ((const float*)&xc)[c];
      const float4 w0q = wc[c * 2], w1q = wc[c * 2 + 1];
      acc[0] = fmaf(xs, w0q.x, acc[0]); acc[1] = fmaf(xs, w0q.y, acc[1]);
      acc[2] = fmaf(xs, w0q.z, acc[2]); acc[3] = fmaf(xs, w0q.w, acc[3]);
      acc[4] = fmaf(xs, w1q.x, acc[4]); acc[5] = fmaf(xs, w1q.y, acc[5]);
      acc[6] = fmaf(xs, w1q.z, acc[6]); acc[7] = fmaf(xs, w1q.w, acc[7]);
    }
  }
  { // peeled d = 120 (consumes last prefetch)
    const float4 xc = sXv[lane + 120];
#pragma unroll
    for (int c = 0; c < 4; ++c) {
      const float xs = ((const float*)&xc)[c];
      const float4 w0q = wn[c * 2], w1q = wn[c * 2 + 1];
      acc[0] = fmaf(xs, w0q.x, acc[0]); acc[1] = fmaf(xs, w0q.y, acc[1]);
      acc[2] = fmaf(xs, w0q.z, acc[2]); acc[3] = fmaf(xs, w0q.w, acc[3]);
      acc[4] = fmaf(xs, w1q.x, acc[4]); acc[5] = fmaf(xs, w1q.y, acc[5]);
      acc[6] = fmaf(xs, w1q.z, acc[6]); acc[7] = fmaf(xs, w1q.w, acc[7]);
    }
  }

  // fast tanh + fold through Wc (partial over this wave's 8 neurons)
  float4 yp; yp.x = 0.f; yp.y = 0.f; yp.z = 0.f; yp.w = 0.f;
#pragma unroll
  for (int n = 0; n < 8; ++n) {
    const float h = 1.f - 2.f / (__expf(2.f * acc[n]) + 1.f);
    const int nb = (octu * 8 + n) * 4;
    yp.x = fmaf(h, sWc[nb + 0], yp.x); yp.y = fmaf(h, sWc[nb + 1], yp.y);
    yp.z = fmaf(h, sWc[nb + 2], yp.z); yp.w = fmaf(h, sWc[nb + 3], yp.w);
  }
  sY[tid] = yp;
  __syncthreads();

  if (tid < TL) {
    const float4 p0 = sY[tid], p1 = sY[tid + 64], p2 = sY[tid + 128],
                 p3 = sY[tid + 192];
    float4 out;
    out.x = p0.x + p1.x + p2.x + p3.x + sWc[128 + 0];
    out.y = p0.y + p1.y + p2.y + p3.y + sWc[128 + 1];
    out.z = p0.z + p1.z + p2.z + p3.z + sWc[128 + 2];
    out.w = p0.w + p1.w + p2.w + p3.w + sWc[128 + 3];
    ((float4*)(y + (size_t)b * L_SEQ * 4))[l0 + tid] = out;
  }
}

// ---------------- stage2: out = relu(win5(y) @ W2 + b2) @ W3 + b3 ----------------
__global__ __launch_bounds__(128) void stage2_kernel(
    const float* __restrict__ y, const float* __restrict__ W2,
    const float* __restrict__ b2, const float* __restrict__ W3,
    const float* __restrict__ b3, float* __restrict__ out) {
  const int g = blockIdx.x * 128 + threadIdx.x;  // 0..32767
  const int b = g >> 12;
  const int l = g & (L_SEQ - 1);
  const float4* yv = (const float4*)(y + (size_t)b * L_SEQ * 4);

  float win[20];
#pragma unroll
  for (int j = 0; j < 5; ++j) {
    const float4 v = yv[(l - 4 + j) & (L_SEQ - 1)];
    win[j*4+0] = v.x; win[j*4+1] = v.y; win[j*4+2] = v.z; win[j*4+3] = v.w;
  }

  float h[32];
#pragma unroll
  for (int n = 0; n < 32; ++n) h[n] = b2[n];
#pragma unroll
  for (int k = 0; k < 20; ++k) {
    const float xs = win[k];
#pragma unroll
    for (int n = 0; n < 32; ++n) h[n] = fmaf(xs, W2[k*32 + n], h[n]);
  }

  float o[4];
#pragma unroll
  for (int j = 0; j < 4; ++j) o[j] = b3[j];
#pragma unroll
  for (int n = 0; n < 32; ++n) {
    const float hv = fmaxf(h[n], 0.f);
#pragma unroll
    for (int j = 0; j < 4; ++j) o[j] = fmaf(hv, W3[n*4 + j], o[j]);
  }
  float4 ov;
  ((float*)&ov)[0] = o[0]; ((float*)&ov)[1] = o[1];
  ((float*)&ov)[2] = o[2]; ((float*)&ov)[3] = o[3];
  ((float4*)out)[g] = ov;
}

extern "C" void kernel_launch(void* const* d_in, const int* in_sizes, int n_in,
                              void* d_out, int out_size, void* d_ws, size_t ws_size,
                              hipStream_t stream) {
  const float* x  = (const float*)d_in[0];   // [8,4096,4]
  const float* W0 = (const float*)d_in[1];   // [484,32]
  const float* b0 = (const float*)d_in[2];   // [32]
  const float* W1 = (const float*)d_in[3];   // [32,512]
  const float* b1 = (const float*)d_in[4];   // [512]
  const float* Ws = (const float*)d_in[5];   // [512,4096]
  const float* bs = (const float*)d_in[6];   // [4096]
  const float* Wr = (const float*)d_in[7];   // [4096,4]
  const float* br = (const float*)d_in[8];   // [4]
  const float* W2 = (const float*)d_in[9];   // [20,32]
  const float* b2 = (const float*)d_in[10];  // [32]
  const float* W3 = (const float*)d_in[11];  // [32,4]
  const float* b3 = (const float*)d_in[12];  // [4]
  float* outp = (float*)d_out;               // [8,4096,4]

  // workspace (floats): T[513*4]=2052 @0, WcBc[132] @2052, y[131072] @2304
  float* T    = (float*)d_ws;
  float* WcBc = T + 2052;
  float* y    = (float*)d_ws + 2304;   // 16B-aligned

  precomp1_kernel<<<129, 256, 0, stream>>>(Ws, bs, Wr, T);
  precomp2_kernel<<<33, 128, 0, stream>>>(W1, b1, br, T, WcBc);
  stage1_kernel<<<512, 256, 0, stream>>>(x, W0, b0, WcBc, y);
  stage2_kernel<<<256, 128, 0, stream>>>(y, W2, b2, W3, b3, outp);
}

// Round 5
// 115.743 us; speedup vs baseline: 1.2000x; 1.1817x over previous
//
#include <hip/hip_runtime.h>
#include <hip/hip_bf16.h>
#include <math.h>

// Model_58488864637193 — algebraic collapse of the 3 stacked linears:
//   Wc = W1 @ (Ws @ Wr)  [32,4],  bc = (b1 @ (Ws@Wr)) + bs@Wr + br  [4]
// Work: 141 GFLOP -> ~1.1 GFLOP, dominated by the ring-121 484->32 tanh layer.
//
// R4 -> R5: SGPR double-buffering failed because SMEM returns out-of-order ->
// only legal wait is lgkmcnt(0) full drain -> no pipelining through the scalar
// pipe. Instead raise FMA-per-drain 4x and waves/SIMD 2x: 512-thread blocks,
// 8 waves = 2 neuron-halves x 4 tap-chunks. Per d: 4 s_load_dwordx16 (64
// uniform weight floats) + 1 ds_read_b128 + 64 FMA (128 cyc) per drain.
// Tap-split needs a pre-tanh cross-wave LDS reduce (lane-contiguous float4
// layout, conflict-free).

#define L_SEQ 4096
#define TL    64    // output rows per stage1 block (= wave width)

// ---------------- precomp1: T[513][4] = [Ws; bs] @ Wr ----------------
__global__ __launch_bounds__(256) void precomp1_kernel(
    const float* __restrict__ Ws, const float* __restrict__ bs,
    const float* __restrict__ Wr, float* __restrict__ T) {
  const int tid  = threadIdx.x;
  const int k    = blockIdx.x * 4 + (tid >> 6);   // wave id = output row
  const int lane = tid & 63;
  if (k >= 513) return;
  const float4* row4 = (const float4*)((k < 512) ? (Ws + (size_t)k * 4096) : bs);
  const float4* Wr4  = (const float4*)Wr;
  float a0 = 0.f, a1 = 0.f, a2 = 0.f, a3 = 0.f;
#pragma unroll 4
  for (int m4 = lane; m4 < 1024; m4 += 64) {
    const float4 rv = row4[m4];
#pragma unroll
    for (int c = 0; c < 4; ++c) {
      const float  xs = ((const float*)&rv)[c];
      const float4 w  = Wr4[m4 * 4 + c];
      a0 = fmaf(xs, w.x, a0); a1 = fmaf(xs, w.y, a1);
      a2 = fmaf(xs, w.z, a2); a3 = fmaf(xs, w.w, a3);
    }
  }
#pragma unroll
  for (int off = 32; off > 0; off >>= 1) {
    a0 += __shfl_xor(a0, off); a1 += __shfl_xor(a1, off);
    a2 += __shfl_xor(a2, off); a3 += __shfl_xor(a3, off);
  }
  if (lane == 0) {
    float4 o; o.x = a0; o.y = a1; o.z = a2; o.w = a3;
    ((float4*)T)[k] = o;
  }
}

// ---------------- precomp2: WcBc[132] = {Wc[32][4] row-major, bc[4]} ----------------
__global__ __launch_bounds__(128) void precomp2_kernel(
    const float* __restrict__ W1, const float* __restrict__ b1,
    const float* __restrict__ br, const float* __restrict__ T,
    float* __restrict__ WcBc) {
  const int i   = blockIdx.x;        // 0..32
  const int t   = threadIdx.x;       // 0..127
  const int j   = t & 3;
  const int seg = t >> 2;            // 0..31
  const float4* v4 = (const float4*)((i < 32) ? (W1 + (size_t)i * 512) : b1);
  const float4* T4 = (const float4*)T;
  float acc = 0.f;
#pragma unroll
  for (int q = 0; q < 4; ++q) {
    const int m4 = seg * 4 + q;
    const float4 vv = v4[m4];
#pragma unroll
    for (int c = 0; c < 4; ++c) {
      const float4 trow = T4[m4 * 4 + c];
      acc = fmaf(((const float*)&vv)[c], ((const float*)&trow)[j], acc);
    }
  }
  __shared__ float red[128];
  red[t] = acc;
  __syncthreads();
#pragma unroll
  for (int s = 64; s >= 4; s >>= 1) {
    if (t < s) red[t] += red[t + s];
    __syncthreads();
  }
  if (t < 4) {
    float r = red[t];
    if (i == 32) r += T[512 * 4 + t] + br[t];
    WcBc[(i < 32 ? i * 4 : 128) + t] = r;
  }
}

// ---------------- stage1: y = tanh(win121(x) @ W0 + b0) @ Wc + bc ----------------
// 512 blocks x 512 threads (8 waves). wave w: neuron half oh=w&1 (16 neurons),
// tap chunk tc=w>>1 (30/31 of 121 taps), 64 rows. Weights via uniform scalar
// loads (4 x s_load_dwordx16 per d). Pre-tanh partials reduced across the 4
// tap-chunk waves through LDS, then bias+tanh+Wc fold with wave-uniform g=w.
__global__ __launch_bounds__(512) void stage1_kernel(
    const float* __restrict__ x, const float* __restrict__ W0,
    const float* __restrict__ b0, const float* __restrict__ WcBc,
    float* __restrict__ y) {
  __shared__ float4 sXv[TL + 120];      // 184 * 16 B = 2944 B
  __shared__ float4 sPre[4 * 8 * 64];   // [q][w][r] = 32 KB, lane-contiguous in r
  __shared__ float4 sY2[8 * 64];        // [g][r] = 8 KB

  const int b    = blockIdx.x >> 6;     // 8 batches x 64 tiles
  const int tile = blockIdx.x & 63;
  const int l0   = tile * TL;
  const int tid  = threadIdx.x;
  const int lane = tid & 63;

  const float4* xv = (const float4*)(x + (size_t)b * L_SEQ * 4);
  for (int i = tid; i < TL + 120; i += 512)
    sXv[i] = xv[(l0 - 120 + i) & (L_SEQ - 1)];
  __syncthreads();

  const int w  = __builtin_amdgcn_readfirstlane(tid >> 6);  // 0..7, uniform
  const int oh = w & 1;                 // neuron half: neurons oh*16..+16
  const int tc = w >> 1;                // tap chunk
  const int d0 = tc * 30;
  const int dn = (tc < 3) ? 30 : 31;    // 30+30+30+31 = 121

  const float* __restrict__ Wb = W0 + oh * 16;

  float acc[16];
#pragma unroll
  for (int n = 0; n < 16; ++n) acc[n] = 0.f;

  for (int dd = 0; dd < dn; ++dd) {
    const int d = d0 + dd;
    const float4 xc = sXv[lane + d];                  // 1 ds_read_b128
#pragma unroll
    for (int c = 0; c < 4; ++c) {
      const float* wr_ = Wb + (size_t)(d * 4 + c) * 32;   // uniform address
      const float4 w0 = *(const float4*)(wr_);            // 4x -> s_load_dwordx16
      const float4 w1 = *(const float4*)(wr_ + 4);
      const float4 w2 = *(const float4*)(wr_ + 8);
      const float4 w3 = *(const float4*)(wr_ + 12);
      const float xs = ((const float*)&xc)[c];
      acc[ 0] = fmaf(xs, w0.x, acc[ 0]); acc[ 1] = fmaf(xs, w0.y, acc[ 1]);
      acc[ 2] = fmaf(xs, w0.z, acc[ 2]); acc[ 3] = fmaf(xs, w0.w, acc[ 3]);
      acc[ 4] = fmaf(xs, w1.x, acc[ 4]); acc[ 5] = fmaf(xs, w1.y, acc[ 5]);
      acc[ 6] = fmaf(xs, w1.z, acc[ 6]); acc[ 7] = fmaf(xs, w1.w, acc[ 7]);
      acc[ 8] = fmaf(xs, w2.x, acc[ 8]); acc[ 9] = fmaf(xs, w2.y, acc[ 9]);
      acc[10] = fmaf(xs, w2.z, acc[10]); acc[11] = fmaf(xs, w2.w, acc[11]);
      acc[12] = fmaf(xs, w3.x, acc[12]); acc[13] = fmaf(xs, w3.y, acc[13]);
      acc[14] = fmaf(xs, w3.z, acc[14]); acc[15] = fmaf(xs, w3.w, acc[15]);
    }
  }

  // scatter partials: sPre[q][w][lane], lane-contiguous -> conflict-free
#pragma unroll
  for (int q = 0; q < 4; ++q) {
    float4 v;
    v.x = acc[q*4+0]; v.y = acc[q*4+1]; v.z = acc[q*4+2]; v.w = acc[q*4+3];
    sPre[(q * 8 + w) * 64 + lane] = v;
  }
  __syncthreads();

  // reduce the 4 tap-chunks; per wave the global neuron-quad g == w (uniform).
  // quad g covers neurons 4g..4g+3 = half oh=g>>2, local quad q=g&3.
  {
    const int g   = w;
    const int ohg = g >> 2;
    const int qg  = g & 3;
    float4 s = sPre[(qg * 8 + (0 * 2 + ohg)) * 64 + lane];
#pragma unroll
    for (int t2 = 1; t2 < 4; ++t2) {
      const float4 p = sPre[(qg * 8 + (t2 * 2 + ohg)) * 64 + lane];
      s.x += p.x; s.y += p.y; s.z += p.z; s.w += p.w;
    }
    const float4 bb = *(const float4*)(b0 + g * 4);         // uniform
    const float h0 = 1.f - 2.f / (__expf(2.f * (s.x + bb.x)) + 1.f);
    const float h1 = 1.f - 2.f / (__expf(2.f * (s.y + bb.y)) + 1.f);
    const float h2 = 1.f - 2.f / (__expf(2.f * (s.z + bb.z)) + 1.f);
    const float h3 = 1.f - 2.f / (__expf(2.f * (s.w + bb.w)) + 1.f);
    const float4 wc0 = *(const float4*)(WcBc + (4 * g + 0) * 4);  // uniform
    const float4 wc1 = *(const float4*)(WcBc + (4 * g + 1) * 4);
    const float4 wc2 = *(const float4*)(WcBc + (4 * g + 2) * 4);
    const float4 wc3 = *(const float4*)(WcBc + (4 * g + 3) * 4);
    float4 yp;
    yp.x = h0*wc0.x + h1*wc1.x + h2*wc2.x + h3*wc3.x;
    yp.y = h0*wc0.y + h1*wc1.y + h2*wc2.y + h3*wc3.y;
    yp.z = h0*wc0.z + h1*wc1.z + h2*wc2.z + h3*wc3.z;
    yp.w = h0*wc0.w + h1*wc1.w + h2*wc2.w + h3*wc3.w;
    sY2[g * 64 + lane] = yp;
  }
  __syncthreads();

  if (tid < TL) {
    float4 o;
    o.x = WcBc[128 + 0]; o.y = WcBc[128 + 1];
    o.z = WcBc[128 + 2]; o.w = WcBc[128 + 3];
#pragma unroll
    for (int g2 = 0; g2 < 8; ++g2) {
      const float4 p = sY2[g2 * 64 + tid];
      o.x += p.x; o.y += p.y; o.z += p.z; o.w += p.w;
    }
    ((float4*)(y + (size_t)b * L_SEQ * 4))[l0 + tid] = o;
  }
}

// ---------------- stage2: out = relu(win5(y) @ W2 + b2) @ W3 + b3 ----------------
__global__ __launch_bounds__(128) void stage2_kernel(
    const float* __restrict__ y, const float* __restrict__ W2,
    const float* __restrict__ b2, const float* __restrict__ W3,
    const float* __restrict__ b3, float* __restrict__ out) {
  const int g = blockIdx.x * 128 + threadIdx.x;  // 0..32767
  const int b = g >> 12;
  const int l = g & (L_SEQ - 1);
  const float4* yv = (const float4*)(y + (size_t)b * L_SEQ * 4);

  float win[20];
#pragma unroll
  for (int j = 0; j < 5; ++j) {
    const float4 v = yv[(l - 4 + j) & (L_SEQ - 1)];
    win[j*4+0] = v.x; win[j*4+1] = v.y; win[j*4+2] = v.z; win[j*4+3] = v.w;
  }

  float h[32];
#pragma unroll
  for (int n = 0; n < 32; ++n) h[n] = b2[n];
#pragma unroll
  for (int k = 0; k < 20; ++k) {
    const float xs = win[k];
#pragma unroll
    for (int n = 0; n < 32; ++n) h[n] = fmaf(xs, W2[k*32 + n], h[n]);
  }

  float o[4];
#pragma unroll
  for (int j = 0; j < 4; ++j) o[j] = b3[j];
#pragma unroll
  for (int n = 0; n < 32; ++n) {
    const float hv = fmaxf(h[n], 0.f);
#pragma unroll
    for (int j = 0; j < 4; ++j) o[j] = fmaf(hv, W3[n*4 + j], o[j]);
  }
  float4 ov;
  ((float*)&ov)[0] = o[0]; ((float*)&ov)[1] = o[1];
  ((float*)&ov)[2] = o[2]; ((float*)&ov)[3] = o[3];
  ((float4*)out)[g] = ov;
}

extern "C" void kernel_launch(void* const* d_in, const int* in_sizes, int n_in,
                              void* d_out, int out_size, void* d_ws, size_t ws_size,
                              hipStream_t stream) {
  const float* x  = (const float*)d_in[0];   // [8,4096,4]
  const float* W0 = (const float*)d_in[1];   // [484,32]
  const float* b0 = (const float*)d_in[2];   // [32]
  const float* W1 = (const float*)d_in[3];   // [32,512]
  const float* b1 = (const float*)d_in[4];   // [512]
  const float* Ws = (const float*)d_in[5];   // [512,4096]
  const float* bs = (const float*)d_in[6];   // [4096]
  const float* Wr = (const float*)d_in[7];   // [4096,4]
  const float* br = (const float*)d_in[8];   // [4]
  const float* W2 = (const float*)d_in[9];   // [20,32]
  const float* b2 = (const float*)d_in[10];  // [32]
  const float* W3 = (const float*)d_in[11];  // [32,4]
  const float* b3 = (const float*)d_in[12];  // [4]
  float* outp = (float*)d_out;               // [8,4096,4]

  // workspace (floats): T[513*4]=2052 @0, WcBc[132] @2052, y[131072] @2304
  float* T    = (float*)d_ws;
  float* WcBc = T + 2052;
  float* y    = (float*)d_ws + 2304;   // 16B-aligned

  precomp1_kernel<<<129, 256, 0, stream>>>(Ws, bs, Wr, T);
  precomp2_kernel<<<33, 128, 0, stream>>>(W1, b1, br, T, WcBc);
  stage1_kernel<<<512, 512, 0, stream>>>(x, W0, b0, WcBc, y);
  stage2_kernel<<<256, 128, 0, stream>>>(y, W2, b2, W3, b3, outp);
}